// Round 1
// baseline (215.902 us; speedup 1.0000x reference)
//
#include <hip/hip_runtime.h>
#include <math.h>

// SimTALayer: out[b,i,:] = sum_{j<=i} p_ij * h_j,  p_ij = softmax_j<=i(-L*(c_i-c_j)+beta)
// = EMA recurrence: S_i = a_i*S_{i-1} + h_i, Z_i = a_i*Z_{i-1} + 1, a_i = exp(-L*tau_i),
//   out_i = S_i/Z_i.  (beta cancels in softmax; NINF rows underflow to exact 0.)
// Exact chunked-scan parallelization (no windowing approximation).

#define BB 4
#define TT 4096
#define DIN 64
#define DM 256
#define TC 64            // chunk length
#define NC (TT / TC)     // 64 chunks per batch

// ---------- Kernel A: h = elu(x @ W^T + b) ----------
__global__ void k_gemm_elu(const float* __restrict__ x, const float* __restrict__ W,
                           const float* __restrict__ bias, float* __restrict__ h) {
    const int t = blockIdx.x;        // flattened (b,t) row: 0..BB*TT-1
    const int m = threadIdx.x;       // 0..255
    __shared__ float xs[DIN];
    if (m < DIN) xs[m] = x[(size_t)t * DIN + m];
    __syncthreads();
    const float4* W4 = reinterpret_cast<const float4*>(W + (size_t)m * DIN);
    float acc = bias[m];
#pragma unroll
    for (int k4 = 0; k4 < DIN / 4; ++k4) {
        float4 w = W4[k4];
        acc = fmaf(xs[4 * k4 + 0], w.x, acc);
        acc = fmaf(xs[4 * k4 + 1], w.y, acc);
        acc = fmaf(xs[4 * k4 + 2], w.z, acc);
        acc = fmaf(xs[4 * k4 + 3], w.w, acc);
    }
    h[(size_t)t * DM + m] = acc > 0.f ? acc : expm1f(acc);
}

// ---------- Kernel B: per-chunk local scan (zero initial state) ----------
__global__ void k_chunk_local(const float* __restrict__ tau, const float* __restrict__ h,
                              const float* __restrict__ lamb_p,
                              float* __restrict__ SL, float* __restrict__ ZL,
                              float* __restrict__ AK) {
    const int blk = blockIdx.x;           // b*NC + c
    const int b = blk / NC, c = blk % NC;
    const int m = threadIdx.x;
    const int t0 = c * TC;
    const float L = fmaxf(lamb_p[0], 0.f);
    __shared__ float as[TC];
    if (m < TC) as[m] = expf(-L * tau[(size_t)b * TT + t0 + m]);
    __syncthreads();
    float S = 0.f, Z = 0.f, A = 1.f;
    const float* hp = h + ((size_t)b * TT + t0) * DM + m;
#pragma unroll
    for (int t = 0; t < TC; ++t) {
        const float a = as[t];
        S = fmaf(a, S, hp[(size_t)t * DM]);
        Z = fmaf(a, Z, 1.f);
        A *= a;
    }
    SL[(size_t)blk * DM + m] = S;
    if (m == 0) { ZL[blk] = Z; AK[blk] = A; }
}

// ---------- Kernel C: sequential carry composition over chunks (per b) ----------
__global__ void k_carry(const float* __restrict__ SL, const float* __restrict__ ZL,
                        const float* __restrict__ AK,
                        float* __restrict__ CS, float* __restrict__ CZ) {
    const int b = blockIdx.x;
    const int m = threadIdx.x;
    float carS = 0.f, carZ = 0.f;
#pragma unroll
    for (int c = 0; c < NC; ++c) {
        const int blk = b * NC + c;
        CS[(size_t)blk * DM + m] = carS;   // carry-IN (state before chunk c)
        if (m == 0) CZ[blk] = carZ;
        const float A = AK[blk];
        carS = fmaf(A, carS, SL[(size_t)blk * DM + m]);
        carZ = fmaf(A, carZ, ZL[blk]);
    }
}

// ---------- Kernel D: final scan with carry-in, write out = S/Z ----------
__global__ void k_chunk_final(const float* __restrict__ tau, const float* __restrict__ h,
                              const float* __restrict__ lamb_p,
                              const float* __restrict__ CS, const float* __restrict__ CZ,
                              float* __restrict__ out) {
    const int blk = blockIdx.x;
    const int b = blk / NC, c = blk % NC;
    const int m = threadIdx.x;
    const int t0 = c * TC;
    const float L = fmaxf(lamb_p[0], 0.f);
    __shared__ float as[TC];
    if (m < TC) as[m] = expf(-L * tau[(size_t)b * TT + t0 + m]);
    __syncthreads();
    float S = CS[(size_t)blk * DM + m];
    float Z = CZ[blk];
    const float* hp = h + ((size_t)b * TT + t0) * DM + m;
    float* op = out + ((size_t)b * TT + t0) * DM + m;
#pragma unroll
    for (int t = 0; t < TC; ++t) {
        const float a = as[t];
        S = fmaf(a, S, hp[(size_t)t * DM]);
        Z = fmaf(a, Z, 1.f);
        op[(size_t)t * DM] = S / Z;
    }
}

extern "C" void kernel_launch(void* const* d_in, const int* in_sizes, int n_in,
                              void* d_out, int out_size, void* d_ws, size_t ws_size,
                              hipStream_t stream) {
    const float* x    = (const float*)d_in[0];  // [B,T,64]
    const float* tau  = (const float*)d_in[1];  // [B,T]
    const float* W    = (const float*)d_in[2];  // [256,64]
    const float* bias = (const float*)d_in[3];  // [256]
    const float* lamb = (const float*)d_in[4];  // [1]
    // beta (d_in[5]) cancels in the softmax — unused.
    float* out = (float*)d_out;                 // [B,T,256] fp32

    float* ws = (float*)d_ws;
    float* h  = ws;                                   // B*T*DM      = 4,194,304 f
    float* SL = h  + (size_t)BB * TT * DM;            // B*NC*DM     = 65,536 f
    float* ZL = SL + (size_t)BB * NC * DM;            // B*NC        = 256 f
    float* AK = ZL + BB * NC;                         // B*NC
    float* CS = AK + BB * NC;                         // B*NC*DM
    float* CZ = CS + (size_t)BB * NC * DM;            // B*NC

    k_gemm_elu   <<<BB * TT, DM, 0, stream>>>(x, W, bias, h);
    k_chunk_local<<<BB * NC, DM, 0, stream>>>(tau, h, lamb, SL, ZL, AK);
    k_carry      <<<BB,      DM, 0, stream>>>(SL, ZL, AK, CS, CZ);
    k_chunk_final<<<BB * NC, DM, 0, stream>>>(tau, h, lamb, CS, CZ, out);
}

// Round 2
// 146.832 us; speedup vs baseline: 1.4704x; 1.4704x over previous
//
#include <hip/hip_runtime.h>
#include <math.h>

// SimTALayer == causal softmax attention with score -L*(c_i - c_j) + beta, which
// collapses to an EMA recurrence (beta cancels; upper-tri NINF underflows to 0):
//   a_t = exp(-L*tau_t);  S_t = a_t*S_{t-1} + h_t;  Z_t = a_t*Z_{t-1} + 1;
//   out_t = S_t / Z_t;    h = elu(x @ W^T + b).
// Exact chunked scan, 2 kernels. h is RECOMPUTED per kernel (0.5 GFLOP) instead
// of materialized (48 MB HBM round-trips) — compute is far cheaper than traffic.

#define BB 4
#define TT 4096
#define DIN 64
#define DM 256
#define TC 64            // chunk length
#define NC (TT / TC)     // 64 chunks per batch; grid = BB*NC = 256 = 1 block/CU

// ---------- Kernel 1: per-chunk local scan with fused GEMM+ELU ----------
// Thread m owns channel m: W row m lives in 64 VGPRs (W read once per block ->
// 16 MB aggregate L2 traffic vs 1 GB in the unfused version). x rows are
// wave-uniform loads. 4 timesteps batched -> 4 independent FMA chains.
__global__ __launch_bounds__(256) void k_local(
    const float* __restrict__ x, const float* __restrict__ tau,
    const float* __restrict__ W, const float* __restrict__ bias,
    const float* __restrict__ lamb_p,
    float* __restrict__ SL, float* __restrict__ ZL, float* __restrict__ AK) {
    const int blk = blockIdx.x;
    const int b = blk / NC, c = blk % NC;
    const int t0 = c * TC;
    const int m = threadIdx.x;

    float4 wv[DIN / 4];
    const float4* W4 = reinterpret_cast<const float4*>(W + (size_t)m * DIN);
#pragma unroll
    for (int k = 0; k < DIN / 4; ++k) wv[k] = W4[k];
    const float bm = bias[m];

    __shared__ float as[TC];
    const float L = fmaxf(lamb_p[0], 0.f);
    if (m < TC) as[m] = expf(-L * tau[(size_t)b * TT + t0 + m]);
    __syncthreads();

    const float* xr = x + ((size_t)b * TT + t0) * DIN;
    float S = 0.f, Z = 0.f, A = 1.f;
#pragma unroll
    for (int tg = 0; tg < TC; tg += 4) {
        const float4* xt0 = reinterpret_cast<const float4*>(xr + (size_t)(tg + 0) * DIN);
        const float4* xt1 = reinterpret_cast<const float4*>(xr + (size_t)(tg + 1) * DIN);
        const float4* xt2 = reinterpret_cast<const float4*>(xr + (size_t)(tg + 2) * DIN);
        const float4* xt3 = reinterpret_cast<const float4*>(xr + (size_t)(tg + 3) * DIN);
        float a0 = bm, a1 = bm, a2 = bm, a3 = bm;
#pragma unroll
        for (int k = 0; k < DIN / 4; ++k) {
            const float4 w = wv[k];
            const float4 v0 = xt0[k], v1 = xt1[k], v2 = xt2[k], v3 = xt3[k];
            a0 = fmaf(v0.x, w.x, a0); a0 = fmaf(v0.y, w.y, a0);
            a0 = fmaf(v0.z, w.z, a0); a0 = fmaf(v0.w, w.w, a0);
            a1 = fmaf(v1.x, w.x, a1); a1 = fmaf(v1.y, w.y, a1);
            a1 = fmaf(v1.z, w.z, a1); a1 = fmaf(v1.w, w.w, a1);
            a2 = fmaf(v2.x, w.x, a2); a2 = fmaf(v2.y, w.y, a2);
            a2 = fmaf(v2.z, w.z, a2); a2 = fmaf(v2.w, w.w, a2);
            a3 = fmaf(v3.x, w.x, a3); a3 = fmaf(v3.y, w.y, a3);
            a3 = fmaf(v3.z, w.z, a3); a3 = fmaf(v3.w, w.w, a3);
        }
        const float h0 = a0 > 0.f ? a0 : expm1f(a0);
        const float h1 = a1 > 0.f ? a1 : expm1f(a1);
        const float h2 = a2 > 0.f ? a2 : expm1f(a2);
        const float h3 = a3 > 0.f ? a3 : expm1f(a3);
        float d;
        d = as[tg + 0]; S = fmaf(d, S, h0); Z = fmaf(d, Z, 1.f); A *= d;
        d = as[tg + 1]; S = fmaf(d, S, h1); Z = fmaf(d, Z, 1.f); A *= d;
        d = as[tg + 2]; S = fmaf(d, S, h2); Z = fmaf(d, Z, 1.f); A *= d;
        d = as[tg + 3]; S = fmaf(d, S, h3); Z = fmaf(d, Z, 1.f); A *= d;
    }
    SL[(size_t)blk * DM + m] = S;
    if (m == 0) { ZL[blk] = Z; AK[blk] = A; }
}

// ---------- Kernel 2: carry composition (in-block) + final scan + out ----------
__global__ __launch_bounds__(256) void k_final(
    const float* __restrict__ x, const float* __restrict__ tau,
    const float* __restrict__ W, const float* __restrict__ bias,
    const float* __restrict__ lamb_p,
    const float* __restrict__ SL, const float* __restrict__ ZL,
    const float* __restrict__ AK, float* __restrict__ out) {
    const int blk = blockIdx.x;
    const int b = blk / NC, c = blk % NC;
    const int t0 = c * TC;
    const int m = threadIdx.x;

    float4 wv[DIN / 4];
    const float4* W4 = reinterpret_cast<const float4*>(W + (size_t)m * DIN);
#pragma unroll
    for (int k = 0; k < DIN / 4; ++k) wv[k] = W4[k];
    const float bm = bias[m];

    __shared__ float as[TC];
    const float L = fmaxf(lamb_p[0], 0.f);
    if (m < TC) as[m] = expf(-L * tau[(size_t)b * TT + t0 + m]);
    __syncthreads();

    // Carry-in: compose all preceding chunks of this batch (block-uniform trip count).
    float S = 0.f, Z = 0.f;
    for (int cc = 0; cc < c; ++cc) {
        const int pb = b * NC + cc;
        const float A = AK[pb];
        S = fmaf(A, S, SL[(size_t)pb * DM + m]);
        Z = fmaf(A, Z, ZL[pb]);
    }

    const float* xr = x + ((size_t)b * TT + t0) * DIN;
    float* op = out + ((size_t)b * TT + t0) * DM + m;
#pragma unroll
    for (int tg = 0; tg < TC; tg += 4) {
        const float4* xt0 = reinterpret_cast<const float4*>(xr + (size_t)(tg + 0) * DIN);
        const float4* xt1 = reinterpret_cast<const float4*>(xr + (size_t)(tg + 1) * DIN);
        const float4* xt2 = reinterpret_cast<const float4*>(xr + (size_t)(tg + 2) * DIN);
        const float4* xt3 = reinterpret_cast<const float4*>(xr + (size_t)(tg + 3) * DIN);
        float a0 = bm, a1 = bm, a2 = bm, a3 = bm;
#pragma unroll
        for (int k = 0; k < DIN / 4; ++k) {
            const float4 w = wv[k];
            const float4 v0 = xt0[k], v1 = xt1[k], v2 = xt2[k], v3 = xt3[k];
            a0 = fmaf(v0.x, w.x, a0); a0 = fmaf(v0.y, w.y, a0);
            a0 = fmaf(v0.z, w.z, a0); a0 = fmaf(v0.w, w.w, a0);
            a1 = fmaf(v1.x, w.x, a1); a1 = fmaf(v1.y, w.y, a1);
            a1 = fmaf(v1.z, w.z, a1); a1 = fmaf(v1.w, w.w, a1);
            a2 = fmaf(v2.x, w.x, a2); a2 = fmaf(v2.y, w.y, a2);
            a2 = fmaf(v2.z, w.z, a2); a2 = fmaf(v2.w, w.w, a2);
            a3 = fmaf(v3.x, w.x, a3); a3 = fmaf(v3.y, w.y, a3);
            a3 = fmaf(v3.z, w.z, a3); a3 = fmaf(v3.w, w.w, a3);
        }
        const float h0 = a0 > 0.f ? a0 : expm1f(a0);
        const float h1 = a1 > 0.f ? a1 : expm1f(a1);
        const float h2 = a2 > 0.f ? a2 : expm1f(a2);
        const float h3 = a3 > 0.f ? a3 : expm1f(a3);
        float d;
        d = as[tg + 0]; S = fmaf(d, S, h0); Z = fmaf(d, Z, 1.f); op[(size_t)(tg + 0) * DM] = S / Z;
        d = as[tg + 1]; S = fmaf(d, S, h1); Z = fmaf(d, Z, 1.f); op[(size_t)(tg + 1) * DM] = S / Z;
        d = as[tg + 2]; S = fmaf(d, S, h2); Z = fmaf(d, Z, 1.f); op[(size_t)(tg + 2) * DM] = S / Z;
        d = as[tg + 3]; S = fmaf(d, S, h3); Z = fmaf(d, Z, 1.f); op[(size_t)(tg + 3) * DM] = S / Z;
    }
}

extern "C" void kernel_launch(void* const* d_in, const int* in_sizes, int n_in,
                              void* d_out, int out_size, void* d_ws, size_t ws_size,
                              hipStream_t stream) {
    const float* x    = (const float*)d_in[0];  // [B,T,64]
    const float* tau  = (const float*)d_in[1];  // [B,T]
    const float* W    = (const float*)d_in[2];  // [256,64]
    const float* bias = (const float*)d_in[3];  // [256]
    const float* lamb = (const float*)d_in[4];  // [1]
    // beta (d_in[5]) cancels in softmax — unused.
    float* out = (float*)d_out;                 // [B,T,256] fp32

    float* ws = (float*)d_ws;
    float* SL = ws;                         // BB*NC*DM = 65,536 floats
    float* ZL = SL + (size_t)BB * NC * DM;  // BB*NC = 256
    float* AK = ZL + BB * NC;               // BB*NC = 256

    k_local<<<BB * NC, DM, 0, stream>>>(x, tau, W, bias, lamb, SL, ZL, AK);
    k_final<<<BB * NC, DM, 0, stream>>>(x, tau, W, bias, lamb, SL, ZL, AK, out);
}